// Round 6
// baseline (318.207 us; speedup 1.0000x reference)
//
#include <hip/hip_runtime.h>
#include <hip/hip_bf16.h>
#include <math.h>

#define T_ 128
#define B_ 32
#define V_ 32000
#define E_ 32
#define H_ 16
#define WSEG 4000       // cols per wave (V / 8 waves)
#define WNIT 125        // WSEG / 32 (two 16-col MFMA tiles per iteration)

typedef __attribute__((ext_vector_type(8))) short short8;  // bf16x8 MFMA fragment
typedef __attribute__((ext_vector_type(4))) float f32x4;

// ws layout (float units):
//   xw         [2][T][B][H] f32      @ 0       (131072)
//   featsB     [4096][32]   bf16     @ 131072  (65536)
//   W_hoT      [32000][32]  bf16     @ 196608  (512000)

// Kernel 0: xw[dir][t][b][j] = b_ih[j] + emb[ix[t][b]] @ W[0:E, j]
__global__ __launch_bounds__(256) void xw_kernel(const int* __restrict__ ix,
                                                 const float* __restrict__ emb,
                                                 const float* __restrict__ W_lr,
                                                 const float* __restrict__ b_lr,
                                                 const float* __restrict__ W_rl,
                                                 const float* __restrict__ b_rl,
                                                 float* __restrict__ xw) {
    int idx = blockIdx.x * 256 + threadIdx.x;          // 131072 total
    int j = idx & 15;
    int b = (idx >> 4) & 31;
    int t = (idx >> 9) & 127;
    int dir = idx >> 16;
    const float* W    = dir ? W_rl : W_lr;
    const float* bias = dir ? b_rl : b_lr;
    int tok = ix[t * B_ + b];
    const float* er = emb + (long)tok * E_;
    float acc = bias[j];
#pragma unroll
    for (int e = 0; e < E_; ++e) acc += er[e] * W[e * H_ + j];
    xw[idx] = acc;
}

// Kernel 1: sequential scans, barrier-free (h-exchange via __shfl within a wave).
// Fast tanh: tanh(x) = 1 - 2/(exp(2x)+1); |x| <= ~7.3 so no overflow.
__global__ __launch_bounds__(512) void scan_kernel(const float* __restrict__ xw,
                                                   const float* __restrict__ W_lr,
                                                   const float* __restrict__ W_rl,
                                                   const float* __restrict__ h0p,
                                                   const float* __restrict__ mask_lr,
                                                   const float* __restrict__ mask_rl,
                                                   __hip_bfloat16* __restrict__ featsB) {
    int dir = blockIdx.x;
    int tid = threadIdx.x;
    int lane = tid & 63;
    int j = lane & 15;
    int b = tid >> 4;
    int base = lane & 48;
    const float* W    = dir ? W_rl : W_lr;
    const float* mask = dir ? mask_rl : mask_lr;
    const float* xwd  = xw + dir * (T_ * B_ * H_);
    float Wh[16];
#pragma unroll
    for (int k = 0; k < 16; ++k) Wh[k] = W[(E_ + k) * H_ + j];
    float h = h0p[j];
    if (dir == 0) featsB[(0 * B_ + b) * 32 + j] = __float2bfloat16(h);
    else          featsB[((T_ - 1) * B_ + b) * 32 + 16 + j] = __float2bfloat16(h);

    float x0[4], m0[4], x1[4], m1[4];
#define LOADCH(XB, MB, CH)                                                 \
    _Pragma("unroll")                                                      \
    for (int u = 0; u < 4; ++u) {                                          \
        int t = (CH) * 4 + u;                                              \
        int tt = dir ? (T_ - 1 - t) : t;                                   \
        XB[u] = xwd[tt * (B_ * H_) + tid];                                 \
        MB[u] = mask[tt * (B_ * H_) + tid];                                \
    }
#define STEPS(XB, MB, CH)                                                  \
    _Pragma("unroll")                                                      \
    for (int u = 0; u < 4; ++u) {                                          \
        int t = (CH) * 4 + u;                                              \
        float a0 = XB[u], a1 = 0.f, a2 = 0.f, a3 = 0.f;                    \
        _Pragma("unroll")                                                  \
        for (int k = 0; k < 16; k += 4) {                                  \
            a0 += __shfl(h, base + k,     64) * Wh[k];                     \
            a1 += __shfl(h, base + k + 1, 64) * Wh[k + 1];                 \
            a2 += __shfl(h, base + k + 2, 64) * Wh[k + 2];                 \
            a3 += __shfl(h, base + k + 3, 64) * Wh[k + 3];                 \
        }                                                                  \
        float ax = (a0 + a1) + (a2 + a3);                                  \
        float ex = __expf(2.f * ax);                                       \
        float th = 1.f - 2.f * __builtin_amdgcn_rcpf(ex + 1.f);            \
        float hn = th * MB[u];                                             \
        h = hn;                                                            \
        int p = dir ? (T_ - 2 - t) : (t + 1);                              \
        if (p >= 0 && p < T_)                                              \
            featsB[(p * B_ + b) * 32 + dir * 16 + j] = __float2bfloat16(hn); \
    }
    LOADCH(x0, m0, 0)
#pragma unroll 1
    for (int c = 0; c < 32; c += 2) {
        if (c + 1 < 32) { LOADCH(x1, m1, c + 1) }
        STEPS(x0, m0, c)
        if (c + 2 < 32) { LOADCH(x0, m0, c + 2) }
        STEPS(x1, m1, c + 1)
    }
#undef LOADCH
#undef STEPS
}

// Kernel 1b: W_hoT[c][k] = bf16(W_ho[k][c])
__global__ __launch_bounds__(256) void wt_kernel(const float* __restrict__ W_ho,
                                                 __hip_bfloat16* __restrict__ W_hoT) {
    int c = blockIdx.x * 256 + threadIdx.x;    // 125 blocks -> 32000 exactly
    __hip_bfloat16 tmp[32];
#pragma unroll
    for (int k = 0; k < 32; ++k) tmp[k] = __float2bfloat16(W_ho[k * V_ + c]);
    short8* dst = (short8*)(W_hoT + c * 32);
    const short8* src = (const short8*)tmp;
#pragma unroll
    for (int q = 0; q < 4; ++q) dst[q] = src[q];
}

// Fused kernel: per 16-row tile, phase A computes per-row lse over full V
// (8 waves x 4000-col spans, LDS cross-wave reduce), phase B recomputes the
// logits and writes out = logit - lse with nontemporal f32x4 stores.
// MFMA (16x16x32, swapped: A = W-tile [16 cols x 32 k], B = feats):
//   lane L: p = L&15, kb = (L>>4)*8; D: lane holds row (L&15), cols c0+(L>>4)*4+{0..3}
__global__ __launch_bounds__(512) void softmax_kernel(const __hip_bfloat16* __restrict__ featsB,
                                                      const __hip_bfloat16* __restrict__ W_hoT,
                                                      const float* __restrict__ b_ho,
                                                      float* __restrict__ out) {
    int wv = threadIdx.x >> 6, lane = threadIdx.x & 63;
    int row0 = blockIdx.x * 16;          // 256 blocks
    int p = lane & 15, kb = (lane >> 4) * 8, quad = (lane >> 4) << 2;
    short8 bfrag = *(const short8*)((const short*)featsB + (row0 + p) * 32 + kb);
    int cbase = wv * WSEG;
    const short* WA = (const short*)W_hoT;
    __shared__ float part[8][16];

    // ---- phase A: per-row sum(exp(logit)) over this wave's span ----
    float r0 = 0.f, r1 = 0.f;
    short8 a0n = *(const short8*)(WA + (cbase + p) * 32 + kb);
    short8 a1n = *(const short8*)(WA + (cbase + 16 + p) * 32 + kb);
#pragma unroll 1
    for (int it = 0; it < WNIT; ++it) {
        short8 a0 = a0n, a1 = a1n;
        if (it < WNIT - 1) {
            int cn = cbase + (it + 1) * 32;
            a0n = *(const short8*)(WA + (cn + p) * 32 + kb);
            a1n = *(const short8*)(WA + (cn + 16 + p) * 32 + kb);
        }
        int c0 = cbase + it * 32;
        f32x4 b40 = *(const f32x4*)(b_ho + c0 + quad);
        f32x4 b41 = *(const f32x4*)(b_ho + c0 + 16 + quad);
        f32x4 lg0 = __builtin_amdgcn_mfma_f32_16x16x32_bf16(a0, bfrag, (f32x4){0.f,0.f,0.f,0.f}, 0, 0, 0);
        f32x4 lg1 = __builtin_amdgcn_mfma_f32_16x16x32_bf16(a1, bfrag, (f32x4){0.f,0.f,0.f,0.f}, 0, 0, 0);
        r0 += __expf(lg0[0] + b40[0]) + __expf(lg0[1] + b40[1]) +
              __expf(lg0[2] + b40[2]) + __expf(lg0[3] + b40[3]);
        r1 += __expf(lg1[0] + b41[0]) + __expf(lg1[1] + b41[1]) +
              __expf(lg1[2] + b41[2]) + __expf(lg1[3] + b41[3]);
    }
    float racc = r0 + r1;
    racc += __shfl_xor(racc, 16, 64);
    racc += __shfl_xor(racc, 32, 64);
    if (lane < 16) part[wv][lane] = racc;
    __syncthreads();

    // ---- local lse for this lane's row ----
    float s = 0.f;
#pragma unroll
    for (int w = 0; w < 8; ++w) s += part[w][p];
    float ls = __logf(s);

    // ---- phase B: recompute logits, write out = logit - lse ----
    float* orow = out + (long)(row0 + p) * V_;
    a0n = *(const short8*)(WA + (cbase + p) * 32 + kb);
    a1n = *(const short8*)(WA + (cbase + 16 + p) * 32 + kb);
#pragma unroll 1
    for (int it = 0; it < WNIT; ++it) {
        short8 a0 = a0n, a1 = a1n;
        if (it < WNIT - 1) {
            int cn = cbase + (it + 1) * 32;
            a0n = *(const short8*)(WA + (cn + p) * 32 + kb);
            a1n = *(const short8*)(WA + (cn + 16 + p) * 32 + kb);
        }
        int c0 = cbase + it * 32;
        f32x4 b40 = *(const f32x4*)(b_ho + c0 + quad);
        f32x4 b41 = *(const f32x4*)(b_ho + c0 + 16 + quad);
        f32x4 lg0 = __builtin_amdgcn_mfma_f32_16x16x32_bf16(a0, bfrag, (f32x4){0.f,0.f,0.f,0.f}, 0, 0, 0);
        f32x4 lg1 = __builtin_amdgcn_mfma_f32_16x16x32_bf16(a1, bfrag, (f32x4){0.f,0.f,0.f,0.f}, 0, 0, 0);
        f32x4 o0, o1;
#pragma unroll
        for (int q = 0; q < 4; ++q) {
            o0[q] = lg0[q] + b40[q] - ls;
            o1[q] = lg1[q] + b41[q] - ls;
        }
        __builtin_nontemporal_store(o0, (f32x4*)(orow + c0 + quad));
        __builtin_nontemporal_store(o1, (f32x4*)(orow + c0 + 16 + quad));
    }
}

extern "C" void kernel_launch(void* const* d_in, const int* in_sizes, int n_in,
                              void* d_out, int out_size, void* d_ws, size_t ws_size,
                              hipStream_t stream) {
    const int*   ix      = (const int*)d_in[0];
    const float* emb     = (const float*)d_in[1];
    const float* W_lr    = (const float*)d_in[2];
    const float* b_lr    = (const float*)d_in[3];
    const float* W_rl    = (const float*)d_in[4];
    const float* b_rl    = (const float*)d_in[5];
    const float* W_ho    = (const float*)d_in[6];
    const float* b_ho    = (const float*)d_in[7];
    const float* h0      = (const float*)d_in[8];
    const float* mask_lr = (const float*)d_in[9];
    const float* mask_rl = (const float*)d_in[10];
    float* out = (float*)d_out;
    float* ws  = (float*)d_ws;

    float*           xw     = ws;                                   // 131072
    __hip_bfloat16*  featsB = (__hip_bfloat16*)(ws + 131072);       // 65536
    __hip_bfloat16*  W_hoT  = (__hip_bfloat16*)(ws + 196608);       // 512000

    xw_kernel<<<512, 256, 0, stream>>>(ix, emb, W_lr, b_lr, W_rl, b_rl, xw);
    wt_kernel<<<125, 256, 0, stream>>>(W_ho, W_hoT);
    scan_kernel<<<2, 512, 0, stream>>>(xw, W_lr, W_rl, h0, mask_lr, mask_rl, featsB);
    softmax_kernel<<<256, 512, 0, stream>>>(featsB, W_hoT, b_ho, out);
}

// Round 7
// 221.149 us; speedup vs baseline: 1.4389x; 1.4389x over previous
//
#include <hip/hip_runtime.h>
#include <hip/hip_bf16.h>
#include <math.h>

#define T_ 128
#define B_ 32
#define V_ 32000
#define E_ 32
#define H_ 16
#define NSEG 20         // column segments
#define SEGW 1600       // V/NSEG
#define NIT 25          // SEGW/64 (four 16-col MFMA tiles per iteration)

typedef __attribute__((ext_vector_type(8))) short short8;  // bf16x8 MFMA fragment
typedef __attribute__((ext_vector_type(4))) float f32x4;

// ws layout (float units):
//   xw         [2][T][B][H] f32      @ 0       (131072)
//   featsB     [4096][32]   bf16     @ 131072  (65536)
//   W_hoT      [32000][32]  bf16     @ 196608  (512000)
//   stats_part [4096][20]   f32      @ 708608  (81920)
//   lse        [4096]       f32      @ 790528  (4096)

// Kernel 0: xw[dir][t][b][j] = b_ih[j] + emb[ix[t][b]] @ W[0:E, j]
__global__ __launch_bounds__(256) void xw_kernel(const int* __restrict__ ix,
                                                 const float* __restrict__ emb,
                                                 const float* __restrict__ W_lr,
                                                 const float* __restrict__ b_lr,
                                                 const float* __restrict__ W_rl,
                                                 const float* __restrict__ b_rl,
                                                 float* __restrict__ xw) {
    int idx = blockIdx.x * 256 + threadIdx.x;          // 131072 total
    int j = idx & 15;
    int b = (idx >> 4) & 31;
    int t = (idx >> 9) & 127;
    int dir = idx >> 16;
    const float* W    = dir ? W_rl : W_lr;
    const float* bias = dir ? b_rl : b_lr;
    int tok = ix[t * B_ + b];
    const float* er = emb + (long)tok * E_;
    float acc = bias[j];
#pragma unroll
    for (int e = 0; e < E_; ++e) acc += er[e] * W[e * H_ + j];
    xw[idx] = acc;
}

// Kernel 1: sequential scans, barrier-free (h-exchange via __shfl within a wave).
// Fast tanh: tanh(x) = 1 - 2/(exp(2x)+1); |x| <= ~7.3 so no overflow.
__global__ __launch_bounds__(512) void scan_kernel(const float* __restrict__ xw,
                                                   const float* __restrict__ W_lr,
                                                   const float* __restrict__ W_rl,
                                                   const float* __restrict__ h0p,
                                                   const float* __restrict__ mask_lr,
                                                   const float* __restrict__ mask_rl,
                                                   __hip_bfloat16* __restrict__ featsB) {
    int dir = blockIdx.x;
    int tid = threadIdx.x;
    int lane = tid & 63;
    int j = lane & 15;
    int b = tid >> 4;
    int base = lane & 48;
    const float* W    = dir ? W_rl : W_lr;
    const float* mask = dir ? mask_rl : mask_lr;
    const float* xwd  = xw + dir * (T_ * B_ * H_);
    float Wh[16];
#pragma unroll
    for (int k = 0; k < 16; ++k) Wh[k] = W[(E_ + k) * H_ + j];
    float h = h0p[j];
    if (dir == 0) featsB[(0 * B_ + b) * 32 + j] = __float2bfloat16(h);
    else          featsB[((T_ - 1) * B_ + b) * 32 + 16 + j] = __float2bfloat16(h);

    float x0[4], m0[4], x1[4], m1[4];
#define LOADCH(XB, MB, CH)                                                 \
    _Pragma("unroll")                                                      \
    for (int u = 0; u < 4; ++u) {                                          \
        int t = (CH) * 4 + u;                                              \
        int tt = dir ? (T_ - 1 - t) : t;                                   \
        XB[u] = xwd[tt * (B_ * H_) + tid];                                 \
        MB[u] = mask[tt * (B_ * H_) + tid];                                \
    }
#define STEPS(XB, MB, CH)                                                  \
    _Pragma("unroll")                                                      \
    for (int u = 0; u < 4; ++u) {                                          \
        int t = (CH) * 4 + u;                                              \
        float a0 = XB[u], a1 = 0.f, a2 = 0.f, a3 = 0.f;                    \
        _Pragma("unroll")                                                  \
        for (int k = 0; k < 16; k += 4) {                                  \
            a0 += __shfl(h, base + k,     64) * Wh[k];                     \
            a1 += __shfl(h, base + k + 1, 64) * Wh[k + 1];                 \
            a2 += __shfl(h, base + k + 2, 64) * Wh[k + 2];                 \
            a3 += __shfl(h, base + k + 3, 64) * Wh[k + 3];                 \
        }                                                                  \
        float ax = (a0 + a1) + (a2 + a3);                                  \
        float ex = __expf(2.f * ax);                                       \
        float th = 1.f - 2.f * __builtin_amdgcn_rcpf(ex + 1.f);            \
        float hn = th * MB[u];                                             \
        h = hn;                                                            \
        int p = dir ? (T_ - 2 - t) : (t + 1);                              \
        if (p >= 0 && p < T_)                                              \
            featsB[(p * B_ + b) * 32 + dir * 16 + j] = __float2bfloat16(hn); \
    }
    LOADCH(x0, m0, 0)
#pragma unroll 1
    for (int c = 0; c < 32; c += 2) {
        if (c + 1 < 32) { LOADCH(x1, m1, c + 1) }
        STEPS(x0, m0, c)
        if (c + 2 < 32) { LOADCH(x0, m0, c + 2) }
        STEPS(x1, m1, c + 1)
    }
#undef LOADCH
#undef STEPS
}

// Kernel 1b: W_hoT[c][k] = bf16(W_ho[k][c])
__global__ __launch_bounds__(256) void wt_kernel(const float* __restrict__ W_ho,
                                                 __hip_bfloat16* __restrict__ W_hoT) {
    int c = blockIdx.x * 256 + threadIdx.x;    // 125 blocks -> 32000 exactly
    __hip_bfloat16 tmp[32];
#pragma unroll
    for (int k = 0; k < 32; ++k) tmp[k] = __float2bfloat16(W_ho[k * V_ + c]);
    short8* dst = (short8*)(W_hoT + c * 32);
    const short8* src = (const short8*)tmp;
#pragma unroll
    for (int q = 0; q < 4; ++q) dst[q] = src[q];
}

// MFMA (16x16x32, swapped: A = W-tile [16 cols x 32 k], B = feats):
//   lane L: p = L&15, kb = (L>>4)*8; D: lane holds row (L&15), cols c0+(L>>4)*4+{0..3}

// Kernel 2: per-row sum(exp(logit)). Wave = 16 rows x one 1600-col segment.
// 25 iters x 64 cols; 4 MFMA tiles per iteration, all 4 afrags prefetched 1 ahead.
__global__ __launch_bounds__(256) void stats_kernel(const __hip_bfloat16* __restrict__ featsB,
                                                    const __hip_bfloat16* __restrict__ W_hoT,
                                                    const float* __restrict__ b_ho,
                                                    float* __restrict__ stats_part) {
    int wv = threadIdx.x >> 6, lane = threadIdx.x & 63;
    int rt = blockIdx.x * 4 + wv;        // 0..255
    int seg = blockIdx.y;                // 0..19
    int row0 = rt * 16;
    int p = lane & 15, kb = (lane >> 4) * 8, quad = (lane >> 4) << 2;
    short8 bfrag = *(const short8*)((const short*)featsB + (row0 + p) * 32 + kb);
    int cbase = seg * SEGW;
    const short* WA = (const short*)W_hoT;
    short8 a0n = *(const short8*)(WA + (cbase +  0 + p) * 32 + kb);
    short8 a1n = *(const short8*)(WA + (cbase + 16 + p) * 32 + kb);
    short8 a2n = *(const short8*)(WA + (cbase + 32 + p) * 32 + kb);
    short8 a3n = *(const short8*)(WA + (cbase + 48 + p) * 32 + kb);
    float r0 = 0.f, r1 = 0.f, r2 = 0.f, r3 = 0.f;
#pragma unroll 1
    for (int it = 0; it < NIT; ++it) {
        short8 a0 = a0n, a1 = a1n, a2 = a2n, a3 = a3n;
        if (it < NIT - 1) {
            int cn = cbase + (it + 1) * 64;
            a0n = *(const short8*)(WA + (cn +  0 + p) * 32 + kb);
            a1n = *(const short8*)(WA + (cn + 16 + p) * 32 + kb);
            a2n = *(const short8*)(WA + (cn + 32 + p) * 32 + kb);
            a3n = *(const short8*)(WA + (cn + 48 + p) * 32 + kb);
        }
        int c0 = cbase + it * 64;
        f32x4 b40 = *(const f32x4*)(b_ho + c0 +  0 + quad);
        f32x4 b41 = *(const f32x4*)(b_ho + c0 + 16 + quad);
        f32x4 b42 = *(const f32x4*)(b_ho + c0 + 32 + quad);
        f32x4 b43 = *(const f32x4*)(b_ho + c0 + 48 + quad);
        f32x4 lg0 = __builtin_amdgcn_mfma_f32_16x16x32_bf16(a0, bfrag, (f32x4){0.f,0.f,0.f,0.f}, 0, 0, 0);
        f32x4 lg1 = __builtin_amdgcn_mfma_f32_16x16x32_bf16(a1, bfrag, (f32x4){0.f,0.f,0.f,0.f}, 0, 0, 0);
        f32x4 lg2 = __builtin_amdgcn_mfma_f32_16x16x32_bf16(a2, bfrag, (f32x4){0.f,0.f,0.f,0.f}, 0, 0, 0);
        f32x4 lg3 = __builtin_amdgcn_mfma_f32_16x16x32_bf16(a3, bfrag, (f32x4){0.f,0.f,0.f,0.f}, 0, 0, 0);
        r0 += __expf(lg0[0] + b40[0]) + __expf(lg0[1] + b40[1]) +
              __expf(lg0[2] + b40[2]) + __expf(lg0[3] + b40[3]);
        r1 += __expf(lg1[0] + b41[0]) + __expf(lg1[1] + b41[1]) +
              __expf(lg1[2] + b41[2]) + __expf(lg1[3] + b41[3]);
        r2 += __expf(lg2[0] + b42[0]) + __expf(lg2[1] + b42[1]) +
              __expf(lg2[2] + b42[2]) + __expf(lg2[3] + b42[3]);
        r3 += __expf(lg3[0] + b43[0]) + __expf(lg3[1] + b43[1]) +
              __expf(lg3[2] + b43[2]) + __expf(lg3[3] + b43[3]);
    }
    float racc = (r0 + r1) + (r2 + r3);
    racc += __shfl_xor(racc, 16, 64);
    racc += __shfl_xor(racc, 32, 64);
    if (lane < 16) stats_part[(row0 + lane) * NSEG + seg] = racc;
}

// Kernel 2b: lse[row] = log(sum of 20 segment partials)
__global__ __launch_bounds__(256) void lse_kernel(const float* __restrict__ stats_part,
                                                  float* __restrict__ lse) {
    int r = blockIdx.x * 256 + threadIdx.x;   // 16 blocks -> 4096
    const float* sp = stats_part + r * NSEG;
    float s = 0.f;
#pragma unroll
    for (int i = 0; i < NSEG; ++i) s += sp[i];
    lse[r] = __logf(s);
}

// Kernel 3: out = logit - lse. Results staged through a per-wave LDS tile
// (16 rows x 64 cols, stride 68 to dodge bank conflicts) so each global store
// writes 4 rows x 256 B fully contiguous (full-line streaming writes).
__global__ __launch_bounds__(256) void out_kernel(const __hip_bfloat16* __restrict__ featsB,
                                                  const __hip_bfloat16* __restrict__ W_hoT,
                                                  const float* __restrict__ b_ho,
                                                  const float* __restrict__ lse,
                                                  float* __restrict__ out) {
    __shared__ float tile[4][16][68];
    int wv = threadIdx.x >> 6, lane = threadIdx.x & 63;
    int rt = blockIdx.x * 4 + wv;
    int seg = blockIdx.y;
    int row0 = rt * 16;
    int p = lane & 15, kb = (lane >> 4) * 8, quad = (lane >> 4) << 2;
    short8 bfrag = *(const short8*)((const short*)featsB + (row0 + p) * 32 + kb);
    float ls = lse[row0 + p];
    int cbase = seg * SEGW;
    const short* WA = (const short*)W_hoT;
    float* tw = &tile[wv][0][0];
    int rr = lane >> 4;             // 0..3
    int cc = (lane & 15) * 4;       // 0..60
    short8 a0n = *(const short8*)(WA + (cbase +  0 + p) * 32 + kb);
    short8 a1n = *(const short8*)(WA + (cbase + 16 + p) * 32 + kb);
    short8 a2n = *(const short8*)(WA + (cbase + 32 + p) * 32 + kb);
    short8 a3n = *(const short8*)(WA + (cbase + 48 + p) * 32 + kb);
#pragma unroll 1
    for (int it = 0; it < NIT; ++it) {
        short8 a0 = a0n, a1 = a1n, a2 = a2n, a3 = a3n;
        if (it < NIT - 1) {
            int cn = cbase + (it + 1) * 64;
            a0n = *(const short8*)(WA + (cn +  0 + p) * 32 + kb);
            a1n = *(const short8*)(WA + (cn + 16 + p) * 32 + kb);
            a2n = *(const short8*)(WA + (cn + 32 + p) * 32 + kb);
            a3n = *(const short8*)(WA + (cn + 48 + p) * 32 + kb);
        }
        int c0 = cbase + it * 64;
        f32x4 b40 = *(const f32x4*)(b_ho + c0 +  0 + quad);
        f32x4 b41 = *(const f32x4*)(b_ho + c0 + 16 + quad);
        f32x4 b42 = *(const f32x4*)(b_ho + c0 + 32 + quad);
        f32x4 b43 = *(const f32x4*)(b_ho + c0 + 48 + quad);
        f32x4 lg0 = __builtin_amdgcn_mfma_f32_16x16x32_bf16(a0, bfrag, (f32x4){0.f,0.f,0.f,0.f}, 0, 0, 0);
        f32x4 lg1 = __builtin_amdgcn_mfma_f32_16x16x32_bf16(a1, bfrag, (f32x4){0.f,0.f,0.f,0.f}, 0, 0, 0);
        f32x4 lg2 = __builtin_amdgcn_mfma_f32_16x16x32_bf16(a2, bfrag, (f32x4){0.f,0.f,0.f,0.f}, 0, 0, 0);
        f32x4 lg3 = __builtin_amdgcn_mfma_f32_16x16x32_bf16(a3, bfrag, (f32x4){0.f,0.f,0.f,0.f}, 0, 0, 0);
        // fold bias+lse, stage into LDS at [p][16u + quad]
        *(f32x4*)(tw + p * 68 +  0 + quad) = lg0 + b40 - ls;
        *(f32x4*)(tw + p * 68 + 16 + quad) = lg1 + b41 - ls;
        *(f32x4*)(tw + p * 68 + 32 + quad) = lg2 + b42 - ls;
        *(f32x4*)(tw + p * 68 + 48 + quad) = lg3 + b43 - ls;
        // read back coalesced: each store covers 4 rows x 256 B contiguous
#pragma unroll
        for (int s = 0; s < 4; ++s) {
            int r = s * 4 + rr;
            f32x4 v = *(const f32x4*)(tw + r * 68 + cc);
            __builtin_nontemporal_store(v, (f32x4*)(out + (long)(row0 + r) * V_ + c0 + cc));
        }
    }
}

extern "C" void kernel_launch(void* const* d_in, const int* in_sizes, int n_in,
                              void* d_out, int out_size, void* d_ws, size_t ws_size,
                              hipStream_t stream) {
    const int*   ix      = (const int*)d_in[0];
    const float* emb     = (const float*)d_in[1];
    const float* W_lr    = (const float*)d_in[2];
    const float* b_lr    = (const float*)d_in[3];
    const float* W_rl    = (const float*)d_in[4];
    const float* b_rl    = (const float*)d_in[5];
    const float* W_ho    = (const float*)d_in[6];
    const float* b_ho    = (const float*)d_in[7];
    const float* h0      = (const float*)d_in[8];
    const float* mask_lr = (const float*)d_in[9];
    const float* mask_rl = (const float*)d_in[10];
    float* out = (float*)d_out;
    float* ws  = (float*)d_ws;

    float*           xw         = ws;                                   // 131072
    __hip_bfloat16*  featsB     = (__hip_bfloat16*)(ws + 131072);       // 65536
    __hip_bfloat16*  W_hoT      = (__hip_bfloat16*)(ws + 196608);       // 512000
    float*           stats_part = ws + 708608;                          // 81920
    float*           lse        = ws + 790528;                          // 4096

    xw_kernel<<<512, 256, 0, stream>>>(ix, emb, W_lr, b_lr, W_rl, b_rl, xw);
    wt_kernel<<<125, 256, 0, stream>>>(W_ho, W_hoT);
    scan_kernel<<<2, 512, 0, stream>>>(xw, W_lr, W_rl, h0, mask_lr, mask_rl, featsB);
    stats_kernel<<<dim3(64, NSEG), 256, 0, stream>>>(featsB, W_hoT, b_ho, stats_part);
    lse_kernel<<<16, 256, 0, stream>>>(stats_part, lse);
    out_kernel<<<dim3(64, NSEG), 256, 0, stream>>>(featsB, W_hoT, b_ho, lse, out);
}

// Round 8
// 182.011 us; speedup vs baseline: 1.7483x; 1.2150x over previous
//
#include <hip/hip_runtime.h>
#include <hip/hip_bf16.h>
#include <math.h>

#define T_ 128
#define B_ 32
#define V_ 32000
#define E_ 32
#define H_ 16
#define NSEG 20         // column segments
#define SEGW 1600       // V/NSEG
#define NIT 25          // SEGW/64 (four 16-col MFMA tiles per iteration)

typedef __attribute__((ext_vector_type(8))) short short8;  // bf16x8 MFMA fragment
typedef __attribute__((ext_vector_type(4))) float f32x4;

// ws layout (float units):
//   xw         [2][T][B][H] f32      @ 0       (131072)
//   featsB     [4096][32]   bf16     @ 131072  (65536)
//   W_hoT      [32000][32]  bf16     @ 196608  (512000)
//   stats_part [4096][20]   f32      @ 708608  (81920)

// Kernel 0: xw[dir][t][b][j] = b_ih[j] + emb[ix[t][b]] @ W[0:E, j]
__global__ __launch_bounds__(256) void xw_kernel(const int* __restrict__ ix,
                                                 const float* __restrict__ emb,
                                                 const float* __restrict__ W_lr,
                                                 const float* __restrict__ b_lr,
                                                 const float* __restrict__ W_rl,
                                                 const float* __restrict__ b_rl,
                                                 float* __restrict__ xw) {
    int idx = blockIdx.x * 256 + threadIdx.x;          // 131072 total
    int j = idx & 15;
    int b = (idx >> 4) & 31;
    int t = (idx >> 9) & 127;
    int dir = idx >> 16;
    const float* W    = dir ? W_rl : W_lr;
    const float* bias = dir ? b_rl : b_lr;
    int tok = ix[t * B_ + b];
    const float* er = emb + (long)tok * E_;
    float acc = bias[j];
#pragma unroll
    for (int e = 0; e < E_; ++e) acc += er[e] * W[e * H_ + j];
    xw[idx] = acc;
}

// Kernel 1 (fused): blocks 0..15 = scan chains (1 wave each, 4 chains/wave);
// blocks 16..515 = W_ho transpose to bf16. Both only need xw/global inputs,
// so the transpose fills the GPU during the scan's serial-latency window.
__global__ __launch_bounds__(64) void scanwt_kernel(const float* __restrict__ xw,
                                                    const float* __restrict__ W_lr,
                                                    const float* __restrict__ W_rl,
                                                    const float* __restrict__ h0p,
                                                    const float* __restrict__ mask_lr,
                                                    const float* __restrict__ mask_rl,
                                                    __hip_bfloat16* __restrict__ featsB,
                                                    const float* __restrict__ W_ho,
                                                    __hip_bfloat16* __restrict__ W_hoT) {
    if (blockIdx.x >= 16) {
        // ---- wt part: W_hoT[c][k] = bf16(W_ho[k][c]) ----
        int c = (blockIdx.x - 16) * 64 + threadIdx.x;   // 500*64 = 32000 exactly
        __hip_bfloat16 tmp[32];
#pragma unroll
        for (int k = 0; k < 32; ++k) tmp[k] = __float2bfloat16(W_ho[k * V_ + c]);
        short8* dst = (short8*)(W_hoT + c * 32);
        const short8* src = (const short8*)tmp;
#pragma unroll
        for (int q = 0; q < 4; ++q) dst[q] = src[q];
        return;
    }
    // ---- scan part: dir = blk>>3, 4 chains per wave ----
    int lane = threadIdx.x;
    int dir = blockIdx.x >> 3;
    int j = lane & 15;
    int b = (blockIdx.x & 7) * 4 + (lane >> 4);
    int bi = b * 16 + j;                 // index into [B][H] slices
    int base = lane & 48;
    const float* W    = dir ? W_rl : W_lr;
    const float* mask = dir ? mask_rl : mask_lr;
    const float* xwd  = xw + dir * (T_ * B_ * H_);
    float Wh[16];
#pragma unroll
    for (int k = 0; k < 16; ++k) Wh[k] = W[(E_ + k) * H_ + j];
    float h = h0p[j];
    if (dir == 0) featsB[(0 * B_ + b) * 32 + j] = __float2bfloat16(h);
    else          featsB[((T_ - 1) * B_ + b) * 32 + 16 + j] = __float2bfloat16(h);

    float x0[4], m0[4], x1[4], m1[4];
#define LOADCH(XB, MB, CH)                                                 \
    _Pragma("unroll")                                                      \
    for (int u = 0; u < 4; ++u) {                                          \
        int t = (CH) * 4 + u;                                              \
        int tt = dir ? (T_ - 1 - t) : t;                                   \
        XB[u] = xwd[tt * (B_ * H_) + bi];                                  \
        MB[u] = mask[tt * (B_ * H_) + bi];                                 \
    }
#define STEPS(XB, MB, CH)                                                  \
    _Pragma("unroll")                                                      \
    for (int u = 0; u < 4; ++u) {                                          \
        int t = (CH) * 4 + u;                                              \
        float a0 = XB[u], a1 = 0.f, a2 = 0.f, a3 = 0.f;                    \
        _Pragma("unroll")                                                  \
        for (int k = 0; k < 16; k += 4) {                                  \
            a0 += __shfl(h, base + k,     64) * Wh[k];                     \
            a1 += __shfl(h, base + k + 1, 64) * Wh[k + 1];                 \
            a2 += __shfl(h, base + k + 2, 64) * Wh[k + 2];                 \
            a3 += __shfl(h, base + k + 3, 64) * Wh[k + 3];                 \
        }                                                                  \
        float ax = (a0 + a1) + (a2 + a3);                                  \
        float ex = __expf(2.f * ax);                                       \
        float th = 1.f - 2.f * __builtin_amdgcn_rcpf(ex + 1.f);            \
        float hn = th * MB[u];                                             \
        h = hn;                                                            \
        int p = dir ? (T_ - 2 - t) : (t + 1);                              \
        if (p >= 0 && p < T_)                                              \
            featsB[(p * B_ + b) * 32 + dir * 16 + j] = __float2bfloat16(hn); \
    }
    LOADCH(x0, m0, 0)
#pragma unroll 1
    for (int c = 0; c < 32; c += 2) {
        if (c + 1 < 32) { LOADCH(x1, m1, c + 1) }
        STEPS(x0, m0, c)
        if (c + 2 < 32) { LOADCH(x0, m0, c + 2) }
        STEPS(x1, m1, c + 1)
    }
#undef LOADCH
#undef STEPS
}

// MFMA (16x16x32, swapped: A = W-tile [16 cols x 32 k], B = feats):
//   lane L: p = L&15, kb = (L>>4)*8; D: lane holds row (L&15), cols c0+(L>>4)*4+{0..3}

// Kernel 2: per-row sum(exp(logit)). Wave = 32 rows (2 bfrags, 2 MFMAs/afrag)
// x one 1600-col segment; 25 iters x 64 cols, afrags prefetched 1 iter ahead.
__global__ __launch_bounds__(256) void stats_kernel(const __hip_bfloat16* __restrict__ featsB,
                                                    const __hip_bfloat16* __restrict__ W_hoT,
                                                    const float* __restrict__ b_ho,
                                                    float* __restrict__ stats_part) {
    int wv = threadIdx.x >> 6, lane = threadIdx.x & 63;
    int rt = blockIdx.x * 4 + wv;        // 0..127 (32-row tiles)
    int seg = blockIdx.y;                // 0..19
    int row0 = rt * 32;
    int p = lane & 15, kb = (lane >> 4) * 8, quad = (lane >> 4) << 2;
    short8 bf0 = *(const short8*)((const short*)featsB + (row0 + p) * 32 + kb);
    short8 bf1 = *(const short8*)((const short*)featsB + (row0 + 16 + p) * 32 + kb);
    int cbase = seg * SEGW;
    const short* WA = (const short*)W_hoT;
    short8 a0n = *(const short8*)(WA + (cbase +  0 + p) * 32 + kb);
    short8 a1n = *(const short8*)(WA + (cbase + 16 + p) * 32 + kb);
    short8 a2n = *(const short8*)(WA + (cbase + 32 + p) * 32 + kb);
    short8 a3n = *(const short8*)(WA + (cbase + 48 + p) * 32 + kb);
    float ra = 0.f, rb = 0.f;
#pragma unroll 1
    for (int it = 0; it < NIT; ++it) {
        short8 a0 = a0n, a1 = a1n, a2 = a2n, a3 = a3n;
        if (it < NIT - 1) {
            int cn = cbase + (it + 1) * 64;
            a0n = *(const short8*)(WA + (cn +  0 + p) * 32 + kb);
            a1n = *(const short8*)(WA + (cn + 16 + p) * 32 + kb);
            a2n = *(const short8*)(WA + (cn + 32 + p) * 32 + kb);
            a3n = *(const short8*)(WA + (cn + 48 + p) * 32 + kb);
        }
        int c0 = cbase + it * 64;
        f32x4 b40 = *(const f32x4*)(b_ho + c0 +  0 + quad);
        f32x4 b41 = *(const f32x4*)(b_ho + c0 + 16 + quad);
        f32x4 b42 = *(const f32x4*)(b_ho + c0 + 32 + quad);
        f32x4 b43 = *(const f32x4*)(b_ho + c0 + 48 + quad);
        f32x4 la0 = __builtin_amdgcn_mfma_f32_16x16x32_bf16(a0, bf0, (f32x4){0.f,0.f,0.f,0.f}, 0, 0, 0);
        f32x4 lb0 = __builtin_amdgcn_mfma_f32_16x16x32_bf16(a0, bf1, (f32x4){0.f,0.f,0.f,0.f}, 0, 0, 0);
        f32x4 la1 = __builtin_amdgcn_mfma_f32_16x16x32_bf16(a1, bf0, (f32x4){0.f,0.f,0.f,0.f}, 0, 0, 0);
        f32x4 lb1 = __builtin_amdgcn_mfma_f32_16x16x32_bf16(a1, bf1, (f32x4){0.f,0.f,0.f,0.f}, 0, 0, 0);
        f32x4 la2 = __builtin_amdgcn_mfma_f32_16x16x32_bf16(a2, bf0, (f32x4){0.f,0.f,0.f,0.f}, 0, 0, 0);
        f32x4 lb2 = __builtin_amdgcn_mfma_f32_16x16x32_bf16(a2, bf1, (f32x4){0.f,0.f,0.f,0.f}, 0, 0, 0);
        f32x4 la3 = __builtin_amdgcn_mfma_f32_16x16x32_bf16(a3, bf0, (f32x4){0.f,0.f,0.f,0.f}, 0, 0, 0);
        f32x4 lb3 = __builtin_amdgcn_mfma_f32_16x16x32_bf16(a3, bf1, (f32x4){0.f,0.f,0.f,0.f}, 0, 0, 0);
        ra += __expf(la0[0] + b40[0]) + __expf(la0[1] + b40[1]) +
              __expf(la0[2] + b40[2]) + __expf(la0[3] + b40[3]);
        rb += __expf(lb0[0] + b40[0]) + __expf(lb0[1] + b40[1]) +
              __expf(lb0[2] + b40[2]) + __expf(lb0[3] + b40[3]);
        ra += __expf(la1[0] + b41[0]) + __expf(la1[1] + b41[1]) +
              __expf(la1[2] + b41[2]) + __expf(la1[3] + b41[3]);
        rb += __expf(lb1[0] + b41[0]) + __expf(lb1[1] + b41[1]) +
              __expf(lb1[2] + b41[2]) + __expf(lb1[3] + b41[3]);
        ra += __expf(la2[0] + b42[0]) + __expf(la2[1] + b42[1]) +
              __expf(la2[2] + b42[2]) + __expf(la2[3] + b42[3]);
        rb += __expf(lb2[0] + b42[0]) + __expf(lb2[1] + b42[1]) +
              __expf(lb2[2] + b42[2]) + __expf(lb2[3] + b42[3]);
        ra += __expf(la3[0] + b43[0]) + __expf(la3[1] + b43[1]) +
              __expf(la3[2] + b43[2]) + __expf(la3[3] + b43[3]);
        rb += __expf(lb3[0] + b43[0]) + __expf(lb3[1] + b43[1]) +
              __expf(lb3[2] + b43[2]) + __expf(lb3[3] + b43[3]);
    }
    ra += __shfl_xor(ra, 16, 64);
    ra += __shfl_xor(ra, 32, 64);
    rb += __shfl_xor(rb, 16, 64);
    rb += __shfl_xor(rb, 32, 64);
    if (lane < 16) {
        stats_part[(row0 + lane) * NSEG + seg] = ra;
        stats_part[(row0 + 16 + lane) * NSEG + seg] = rb;
    }
}

// Kernel 3: out = logit - lse. lse computed in-prologue from stats_part.
// Biases live in a per-block LDS segment (lgkmcnt, not vmcnt) so the only
// vmcnt waits are for afrags prefetched BEFORE the previous iter's stores
// -> stores pipeline across iterations instead of draining every iter.
__global__ __launch_bounds__(256) void out_kernel(const __hip_bfloat16* __restrict__ featsB,
                                                  const __hip_bfloat16* __restrict__ W_hoT,
                                                  const float* __restrict__ b_ho,
                                                  const float* __restrict__ stats_part,
                                                  float* __restrict__ out) {
    __shared__ float tile[4][16][68];
    __shared__ float bseg[SEGW];
    int wv = threadIdx.x >> 6, lane = threadIdx.x & 63;
    int rt = blockIdx.x * 4 + wv;        // 0..255
    int seg = blockIdx.y;                // 0..19 (shared by all 4 waves)
    int row0 = rt * 16;
    int p = lane & 15, kb = (lane >> 4) * 8, quad = (lane >> 4) << 2;
    int cbase = seg * SEGW;
    // cooperative bias preload (1600 floats)
    for (int i = threadIdx.x; i < SEGW / 4; i += 256)
        *(f32x4*)(bseg + i * 4) = *(const f32x4*)(b_ho + cbase + i * 4);
    // lse for this lane's row (all lanes compute redundantly; no shuffle)
    float s = 0.f;
    const float* sp = stats_part + (row0 + p) * NSEG;
#pragma unroll
    for (int i = 0; i < NSEG; ++i) s += sp[i];
    float ls = __logf(s);
    short8 bfrag = *(const short8*)((const short*)featsB + (row0 + p) * 32 + kb);
    const short* WA = (const short*)W_hoT;
    float* tw = &tile[wv][0][0];
    int rr = lane >> 4;             // 0..3
    int cc = (lane & 15) * 4;       // 0..60
    short8 a0n = *(const short8*)(WA + (cbase +  0 + p) * 32 + kb);
    short8 a1n = *(const short8*)(WA + (cbase + 16 + p) * 32 + kb);
    short8 a2n = *(const short8*)(WA + (cbase + 32 + p) * 32 + kb);
    short8 a3n = *(const short8*)(WA + (cbase + 48 + p) * 32 + kb);
    __syncthreads();                // bseg ready
#pragma unroll 1
    for (int it = 0; it < NIT; ++it) {
        short8 a0 = a0n, a1 = a1n, a2 = a2n, a3 = a3n;
        if (it < NIT - 1) {         // issue next-iter loads BEFORE this iter's stores
            int cn = cbase + (it + 1) * 64;
            a0n = *(const short8*)(WA + (cn +  0 + p) * 32 + kb);
            a1n = *(const short8*)(WA + (cn + 16 + p) * 32 + kb);
            a2n = *(const short8*)(WA + (cn + 32 + p) * 32 + kb);
            a3n = *(const short8*)(WA + (cn + 48 + p) * 32 + kb);
        }
        int co = it * 64;           // offset within segment
        f32x4 b40 = *(const f32x4*)(bseg + co +  0 + quad);
        f32x4 b41 = *(const f32x4*)(bseg + co + 16 + quad);
        f32x4 b42 = *(const f32x4*)(bseg + co + 32 + quad);
        f32x4 b43 = *(const f32x4*)(bseg + co + 48 + quad);
        f32x4 lg0 = __builtin_amdgcn_mfma_f32_16x16x32_bf16(a0, bfrag, (f32x4){0.f,0.f,0.f,0.f}, 0, 0, 0);
        f32x4 lg1 = __builtin_amdgcn_mfma_f32_16x16x32_bf16(a1, bfrag, (f32x4){0.f,0.f,0.f,0.f}, 0, 0, 0);
        f32x4 lg2 = __builtin_amdgcn_mfma_f32_16x16x32_bf16(a2, bfrag, (f32x4){0.f,0.f,0.f,0.f}, 0, 0, 0);
        f32x4 lg3 = __builtin_amdgcn_mfma_f32_16x16x32_bf16(a3, bfrag, (f32x4){0.f,0.f,0.f,0.f}, 0, 0, 0);
        *(f32x4*)(tw + p * 68 +  0 + quad) = lg0 + b40 - ls;
        *(f32x4*)(tw + p * 68 + 16 + quad) = lg1 + b41 - ls;
        *(f32x4*)(tw + p * 68 + 32 + quad) = lg2 + b42 - ls;
        *(f32x4*)(tw + p * 68 + 48 + quad) = lg3 + b43 - ls;
        int c0 = cbase + co;
#pragma unroll
        for (int sN = 0; sN < 4; ++sN) {
            int r = sN * 4 + rr;
            f32x4 v = *(const f32x4*)(tw + r * 68 + cc);
            __builtin_nontemporal_store(v, (f32x4*)(out + (long)(row0 + r) * V_ + c0 + cc));
        }
    }
}

extern "C" void kernel_launch(void* const* d_in, const int* in_sizes, int n_in,
                              void* d_out, int out_size, void* d_ws, size_t ws_size,
                              hipStream_t stream) {
    const int*   ix      = (const int*)d_in[0];
    const float* emb     = (const float*)d_in[1];
    const float* W_lr    = (const float*)d_in[2];
    const float* b_lr    = (const float*)d_in[3];
    const float* W_rl    = (const float*)d_in[4];
    const float* b_rl    = (const float*)d_in[5];
    const float* W_ho    = (const float*)d_in[6];
    const float* b_ho    = (const float*)d_in[7];
    const float* h0      = (const float*)d_in[8];
    const float* mask_lr = (const float*)d_in[9];
    const float* mask_rl = (const float*)d_in[10];
    float* out = (float*)d_out;
    float* ws  = (float*)d_ws;

    float*           xw         = ws;                                   // 131072
    __hip_bfloat16*  featsB     = (__hip_bfloat16*)(ws + 131072);       // 65536
    __hip_bfloat16*  W_hoT      = (__hip_bfloat16*)(ws + 196608);       // 512000
    float*           stats_part = ws + 708608;                          // 81920

    xw_kernel<<<512, 256, 0, stream>>>(ix, emb, W_lr, b_lr, W_rl, b_rl, xw);
    scanwt_kernel<<<516, 64, 0, stream>>>(xw, W_lr, W_rl, h0, mask_lr, mask_rl,
                                          featsB, W_ho, W_hoT);
    stats_kernel<<<dim3(32, NSEG), 256, 0, stream>>>(featsB, W_hoT, b_ho, stats_part);
    out_kernel<<<dim3(64, NSEG), 256, 0, stream>>>(featsB, W_hoT, b_ho, stats_part, out);
}

// Round 9
// 180.089 us; speedup vs baseline: 1.7669x; 1.0107x over previous
//
#include <hip/hip_runtime.h>
#include <hip/hip_bf16.h>
#include <math.h>

#define T_ 128
#define B_ 32
#define V_ 32000
#define E_ 32
#define H_ 16
#define NSEG 20         // column segments
#define SEGW 1600       // V/NSEG
#define NIT 25          // SEGW/64 (four 16-col MFMA tiles per iteration)

typedef __attribute__((ext_vector_type(8))) short short8;  // bf16x8 MFMA fragment
typedef __attribute__((ext_vector_type(4))) float f32x4;

#define MFMA_BF16(A, B) __builtin_amdgcn_mfma_f32_16x16x32_bf16((A), (B), (f32x4){0.f,0.f,0.f,0.f}, 0, 0, 0)

__device__ __forceinline__ float expsum4(f32x4 lg, f32x4 bb) {
    return __expf(lg[0] + bb[0]) + __expf(lg[1] + bb[1]) +
           __expf(lg[2] + bb[2]) + __expf(lg[3] + bb[3]);
}

// ws layout (float units):
//   xw         [2][T][B][H] f32      @ 0       (131072)
//   featsB     [4096][32]   bf16     @ 131072  (65536)
//   W_hoT      [32000][32]  bf16     @ 196608  (512000)
//   stats_part [4096][20]   f32      @ 708608  (81920)

// Kernel 0: xw[dir][t][b][j] = b_ih[j] + emb[ix[t][b]] @ W[0:E, j]
__global__ __launch_bounds__(256) void xw_kernel(const int* __restrict__ ix,
                                                 const float* __restrict__ emb,
                                                 const float* __restrict__ W_lr,
                                                 const float* __restrict__ b_lr,
                                                 const float* __restrict__ W_rl,
                                                 const float* __restrict__ b_rl,
                                                 float* __restrict__ xw) {
    int idx = blockIdx.x * 256 + threadIdx.x;          // 131072 total
    int j = idx & 15;
    int b = (idx >> 4) & 31;
    int t = (idx >> 9) & 127;
    int dir = idx >> 16;
    const float* W    = dir ? W_rl : W_lr;
    const float* bias = dir ? b_rl : b_lr;
    int tok = ix[t * B_ + b];
    const float* er = emb + (long)tok * E_;
    float acc = bias[j];
#pragma unroll
    for (int e = 0; e < E_; ++e) acc += er[e] * W[e * H_ + j];
    xw[idx] = acc;
}

// Kernel 1 (fused): blocks 0..15 = scan chains (1 wave each, 4 chains/wave);
// blocks 16..515 = W_ho transpose to bf16.
__global__ __launch_bounds__(64) void scanwt_kernel(const float* __restrict__ xw,
                                                    const float* __restrict__ W_lr,
                                                    const float* __restrict__ W_rl,
                                                    const float* __restrict__ h0p,
                                                    const float* __restrict__ mask_lr,
                                                    const float* __restrict__ mask_rl,
                                                    __hip_bfloat16* __restrict__ featsB,
                                                    const float* __restrict__ W_ho,
                                                    __hip_bfloat16* __restrict__ W_hoT) {
    if (blockIdx.x >= 16) {
        int c = (blockIdx.x - 16) * 64 + threadIdx.x;   // 500*64 = 32000 exactly
        __hip_bfloat16 tmp[32];
#pragma unroll
        for (int k = 0; k < 32; ++k) tmp[k] = __float2bfloat16(W_ho[k * V_ + c]);
        short8* dst = (short8*)(W_hoT + c * 32);
        const short8* src = (const short8*)tmp;
#pragma unroll
        for (int q = 0; q < 4; ++q) dst[q] = src[q];
        return;
    }
    int lane = threadIdx.x;
    int dir = blockIdx.x >> 3;
    int j = lane & 15;
    int b = (blockIdx.x & 7) * 4 + (lane >> 4);
    int bi = b * 16 + j;
    int base = lane & 48;
    const float* W    = dir ? W_rl : W_lr;
    const float* mask = dir ? mask_rl : mask_lr;
    const float* xwd  = xw + dir * (T_ * B_ * H_);
    float Wh[16];
#pragma unroll
    for (int k = 0; k < 16; ++k) Wh[k] = W[(E_ + k) * H_ + j];
    float h = h0p[j];
    if (dir == 0) featsB[(0 * B_ + b) * 32 + j] = __float2bfloat16(h);
    else          featsB[((T_ - 1) * B_ + b) * 32 + 16 + j] = __float2bfloat16(h);

    float x0[4], m0[4], x1[4], m1[4];
#define LOADCH(XB, MB, CH)                                                 \
    _Pragma("unroll")                                                      \
    for (int u = 0; u < 4; ++u) {                                          \
        int t = (CH) * 4 + u;                                              \
        int tt = dir ? (T_ - 1 - t) : t;                                   \
        XB[u] = xwd[tt * (B_ * H_) + bi];                                  \
        MB[u] = mask[tt * (B_ * H_) + bi];                                 \
    }
#define STEPS(XB, MB, CH)                                                  \
    _Pragma("unroll")                                                      \
    for (int u = 0; u < 4; ++u) {                                          \
        int t = (CH) * 4 + u;                                              \
        float a0 = XB[u], a1 = 0.f, a2 = 0.f, a3 = 0.f;                    \
        _Pragma("unroll")                                                  \
        for (int k = 0; k < 16; k += 4) {                                  \
            a0 += __shfl(h, base + k,     64) * Wh[k];                     \
            a1 += __shfl(h, base + k + 1, 64) * Wh[k + 1];                 \
            a2 += __shfl(h, base + k + 2, 64) * Wh[k + 2];                 \
            a3 += __shfl(h, base + k + 3, 64) * Wh[k + 3];                 \
        }                                                                  \
        float ax = (a0 + a1) + (a2 + a3);                                  \
        float ex = __expf(2.f * ax);                                       \
        float th = 1.f - 2.f * __builtin_amdgcn_rcpf(ex + 1.f);            \
        float hn = th * MB[u];                                             \
        h = hn;                                                            \
        int p = dir ? (T_ - 2 - t) : (t + 1);                              \
        if (p >= 0 && p < T_)                                              \
            featsB[(p * B_ + b) * 32 + dir * 16 + j] = __float2bfloat16(hn); \
    }
    LOADCH(x0, m0, 0)
#pragma unroll 1
    for (int c = 0; c < 32; c += 2) {
        if (c + 1 < 32) { LOADCH(x1, m1, c + 1) }
        STEPS(x0, m0, c)
        if (c + 2 < 32) { LOADCH(x0, m0, c + 2) }
        STEPS(x1, m1, c + 1)
    }
#undef LOADCH
#undef STEPS
}

// MFMA (16x16x32, swapped: A = W-tile [16 cols x 32 k], B = feats):
//   lane L: p = L&15, kb = (L>>4)*8; D: lane holds row (L&15), cols c0+(L>>4)*4+{0..3}

// afrag + bias register-prefetch macros (biases prefetched so compute never
// waits on a load issued after the afrag prefetches -> vmcnt(N>0), pipeline lives)
#define LDA4(d0, d1, d2, d3, itv)                                          \
    d0 = *(const short8*)(WA + (cbase + (itv) * 64 +  0 + p) * 32 + kb);   \
    d1 = *(const short8*)(WA + (cbase + (itv) * 64 + 16 + p) * 32 + kb);   \
    d2 = *(const short8*)(WA + (cbase + (itv) * 64 + 32 + p) * 32 + kb);   \
    d3 = *(const short8*)(WA + (cbase + (itv) * 64 + 48 + p) * 32 + kb);
#define LDB4(d0, d1, d2, d3, itv)                                          \
    d0 = *(const f32x4*)(b_ho + cbase + (itv) * 64 +  0 + quad);           \
    d1 = *(const f32x4*)(b_ho + cbase + (itv) * 64 + 16 + quad);           \
    d2 = *(const f32x4*)(b_ho + cbase + (itv) * 64 + 32 + quad);           \
    d3 = *(const f32x4*)(b_ho + cbase + (itv) * 64 + 48 + quad);

// Kernel 2: per-row sum(exp(logit)). Wave = 32 rows x one 1600-col segment.
// Depth-2 register pipeline on afrags AND biases.
__global__ __launch_bounds__(256) void stats_kernel(const __hip_bfloat16* __restrict__ featsB,
                                                    const __hip_bfloat16* __restrict__ W_hoT,
                                                    const float* __restrict__ b_ho,
                                                    float* __restrict__ stats_part) {
    int wv = threadIdx.x >> 6, lane = threadIdx.x & 63;
    int rt = blockIdx.x * 4 + wv;        // 0..127 (32-row tiles)
    int seg = blockIdx.y;                // 0..19
    int row0 = rt * 32;
    int p = lane & 15, kb = (lane >> 4) * 8, quad = (lane >> 4) << 2;
    short8 bf0 = *(const short8*)((const short*)featsB + (row0 + p) * 32 + kb);
    short8 bf1 = *(const short8*)((const short*)featsB + (row0 + 16 + p) * 32 + kb);
    int cbase = seg * SEGW;
    const short* WA = (const short*)W_hoT;
    short8 pa0, pa1, pa2, pa3, pb0, pb1, pb2, pb3;
    f32x4  ba0, ba1, ba2, ba3, bb0, bb1, bb2, bb3;
    LDA4(pa0, pa1, pa2, pa3, 0)
    LDB4(ba0, ba1, ba2, ba3, 0)
    LDA4(pb0, pb1, pb2, pb3, 1)
    LDB4(bb0, bb1, bb2, bb3, 1)
    float ra = 0.f, rb = 0.f;
#define SBODY(c0, c1, c2, c3, d0, d1, d2, d3)                              \
    ra += expsum4(MFMA_BF16(c0, bf0), d0);                                 \
    rb += expsum4(MFMA_BF16(c0, bf1), d0);                                 \
    ra += expsum4(MFMA_BF16(c1, bf0), d1);                                 \
    rb += expsum4(MFMA_BF16(c1, bf1), d1);                                 \
    ra += expsum4(MFMA_BF16(c2, bf0), d2);                                 \
    rb += expsum4(MFMA_BF16(c2, bf1), d2);                                 \
    ra += expsum4(MFMA_BF16(c3, bf0), d3);                                 \
    rb += expsum4(MFMA_BF16(c3, bf1), d3);
#pragma unroll 1
    for (int it = 0; it < NIT; it += 2) {
        short8 c0 = pa0, c1 = pa1, c2 = pa2, c3 = pa3;
        f32x4  d0 = ba0, d1 = ba1, d2 = ba2, d3 = ba3;
        if (it + 2 < NIT) { LDA4(pa0, pa1, pa2, pa3, it + 2) LDB4(ba0, ba1, ba2, ba3, it + 2) }
        SBODY(c0, c1, c2, c3, d0, d1, d2, d3)
        if (it + 1 < NIT) {
            short8 e0 = pb0, e1 = pb1, e2 = pb2, e3 = pb3;
            f32x4  f0 = bb0, f1 = bb1, f2 = bb2, f3 = bb3;
            if (it + 3 < NIT) { LDA4(pb0, pb1, pb2, pb3, it + 3) LDB4(bb0, bb1, bb2, bb3, it + 3) }
            SBODY(e0, e1, e2, e3, f0, f1, f2, f3)
        }
    }
#undef SBODY
    ra += __shfl_xor(ra, 16, 64);
    ra += __shfl_xor(ra, 32, 64);
    rb += __shfl_xor(rb, 16, 64);
    rb += __shfl_xor(rb, 32, 64);
    if (lane < 16) {
        stats_part[(row0 + lane) * NSEG + seg] = ra;
        stats_part[(row0 + 16 + lane) * NSEG + seg] = rb;
    }
}

// Kernel 3: out = logit - lse. lse from stats_part in-prologue; biases in LDS;
// depth-2 afrag pipeline; staged LDS transpose -> 256 B contiguous NT stores.
__global__ __launch_bounds__(256) void out_kernel(const __hip_bfloat16* __restrict__ featsB,
                                                  const __hip_bfloat16* __restrict__ W_hoT,
                                                  const float* __restrict__ b_ho,
                                                  const float* __restrict__ stats_part,
                                                  float* __restrict__ out) {
    __shared__ float tile[4][16][68];
    __shared__ float bseg[SEGW];
    int wv = threadIdx.x >> 6, lane = threadIdx.x & 63;
    int rt = blockIdx.x * 4 + wv;        // 0..255
    int seg = blockIdx.y;                // 0..19
    int row0 = rt * 16;
    int p = lane & 15, kb = (lane >> 4) * 8, quad = (lane >> 4) << 2;
    int cbase = seg * SEGW;
    for (int i = threadIdx.x; i < SEGW / 4; i += 256)
        *(f32x4*)(bseg + i * 4) = *(const f32x4*)(b_ho + cbase + i * 4);
    float s = 0.f;
    const float* sp = stats_part + (row0 + p) * NSEG;
#pragma unroll
    for (int i = 0; i < NSEG; ++i) s += sp[i];
    float ls = __logf(s);
    short8 bfrag = *(const short8*)((const short*)featsB + (row0 + p) * 32 + kb);
    const short* WA = (const short*)W_hoT;
    float* tw = &tile[wv][0][0];
    int rr = lane >> 4;             // 0..3
    int cc = (lane & 15) * 4;       // 0..60
    short8 pa0, pa1, pa2, pa3, pb0, pb1, pb2, pb3;
    LDA4(pa0, pa1, pa2, pa3, 0)
    LDA4(pb0, pb1, pb2, pb3, 1)
    __syncthreads();                // bseg ready
#define OBODY(itv, c0, c1, c2, c3)                                          \
    {                                                                       \
        int co = (itv) * 64;                                                \
        f32x4 b40 = *(const f32x4*)(bseg + co +  0 + quad);                 \
        f32x4 b41 = *(const f32x4*)(bseg + co + 16 + quad);                 \
        f32x4 b42 = *(const f32x4*)(bseg + co + 32 + quad);                 \
        f32x4 b43 = *(const f32x4*)(bseg + co + 48 + quad);                 \
        f32x4 lg0 = MFMA_BF16(c0, bfrag);                                   \
        f32x4 lg1 = MFMA_BF16(c1, bfrag);                                   \
        f32x4 lg2 = MFMA_BF16(c2, bfrag);                                   \
        f32x4 lg3 = MFMA_BF16(c3, bfrag);                                   \
        *(f32x4*)(tw + p * 68 +  0 + quad) = lg0 + b40 - ls;                \
        *(f32x4*)(tw + p * 68 + 16 + quad) = lg1 + b41 - ls;                \
        *(f32x4*)(tw + p * 68 + 32 + quad) = lg2 + b42 - ls;                \
        *(f32x4*)(tw + p * 68 + 48 + quad) = lg3 + b43 - ls;                \
        int c0g = cbase + co;                                               \
        _Pragma("unroll")                                                   \
        for (int sN = 0; sN < 4; ++sN) {                                    \
            int r = sN * 4 + rr;                                            \
            f32x4 v = *(const f32x4*)(tw + r * 68 + cc);                    \
            __builtin_nontemporal_store(v, (f32x4*)(out + (long)(row0 + r) * V_ + c0g + cc)); \
        }                                                                   \
    }
#pragma unroll 1
    for (int it = 0; it < NIT; it += 2) {
        short8 c0 = pa0, c1 = pa1, c2 = pa2, c3 = pa3;
        if (it + 2 < NIT) { LDA4(pa0, pa1, pa2, pa3, it + 2) }
        OBODY(it, c0, c1, c2, c3)
        if (it + 1 < NIT) {
            short8 e0 = pb0, e1 = pb1, e2 = pb2, e3 = pb3;
            if (it + 3 < NIT) { LDA4(pb0, pb1, pb2, pb3, it + 3) }
            OBODY(it + 1, e0, e1, e2, e3)
        }
    }
#undef OBODY
}

extern "C" void kernel_launch(void* const* d_in, const int* in_sizes, int n_in,
                              void* d_out, int out_size, void* d_ws, size_t ws_size,
                              hipStream_t stream) {
    const int*   ix      = (const int*)d_in[0];
    const float* emb     = (const float*)d_in[1];
    const float* W_lr    = (const float*)d_in[2];
    const float* b_lr    = (const float*)d_in[3];
    const float* W_rl    = (const float*)d_in[4];
    const float* b_rl    = (const float*)d_in[5];
    const float* W_ho    = (const float*)d_in[6];
    const float* b_ho    = (const float*)d_in[7];
    const float* h0      = (const float*)d_in[8];
    const float* mask_lr = (const float*)d_in[9];
    const float* mask_rl = (const float*)d_in[10];
    float* out = (float*)d_out;
    float* ws  = (float*)d_ws;

    float*           xw         = ws;                                   // 131072
    __hip_bfloat16*  featsB     = (__hip_bfloat16*)(ws + 131072);       // 65536
    __hip_bfloat16*  W_hoT      = (__hip_bfloat16*)(ws + 196608);       // 512000
    float*           stats_part = ws + 708608;                          // 81920

    xw_kernel<<<512, 256, 0, stream>>>(ix, emb, W_lr, b_lr, W_rl, b_rl, xw);
    scanwt_kernel<<<516, 64, 0, stream>>>(xw, W_lr, W_rl, h0, mask_lr, mask_rl,
                                          featsB, W_ho, W_hoT);
    stats_kernel<<<dim3(32, NSEG), 256, 0, stream>>>(featsB, W_hoT, b_ho, stats_part);
    out_kernel<<<dim3(64, NSEG), 256, 0, stream>>>(featsB, W_hoT, b_ho, stats_part, out);
}